// Round 7
// baseline (122.760 us; speedup 1.0000x reference)
//
#include <hip/hip_runtime.h>
#include <cstdint>
#include <cstddef>

#define D_MODEL 1024
#define NHEADS  16
#define DK      64
#define BATCH   2
#define SEQ     2048
#define MTOT    (BATCH*SEQ)   // 4096
#define NT      (SEQ/64)      // 32

typedef unsigned short u16;
typedef __attribute__((ext_vector_type(8))) __bf16 bf16x8;
typedef __attribute__((ext_vector_type(4))) float  f32x4;
typedef __attribute__((ext_vector_type(4))) uint32_t u32x4;

// softmax scale folded into q-projection: 1/sqrt(64) * log2(e)
#define QSCALE 0.18033688f

static __device__ __forceinline__ void gload16(const void* g, void* l) {
  __builtin_amdgcn_global_load_lds((const __attribute__((address_space(1))) void*)g,
                                   (__attribute__((address_space(3))) void*)l,
                                   16, 0, 0);
}

// ---------------- fused fp32 -> bf16 cast of all 7 tensors ----------------
__global__ void cast_all_kernel(
    const float* __restrict__ Q, const float* __restrict__ K, const float* __restrict__ V,
    const float* __restrict__ Wq, const float* __restrict__ Wk,
    const float* __restrict__ Wv, const float* __restrict__ Wo,
    u16* __restrict__ dstX, u16* __restrict__ dstW) {
  constexpr int NX = MTOT * D_MODEL;      // 4194304
  constexpr int NW = D_MODEL * D_MODEL;   // 1048576
  const int i = (blockIdx.x * blockDim.x + threadIdx.x) * 4;
  const float* src;
  u16* dst;
  if (i < 3 * NX) {
    dst = dstX + i;
    src = (i < NX) ? Q + i : (i < 2 * NX) ? K + (i - NX) : V + (i - 2 * NX);
  } else {
    const int j = i - 3 * NX;
    dst = dstW + j;
    const int ws = j >> 20;                // NW = 2^20
    const int jo = j & (NW - 1);
    src = (ws == 0) ? Wq + jo : (ws == 1) ? Wk + jo : (ws == 2) ? Wv + jo : Wo + jo;
  }
  float4 f = *reinterpret_cast<const float4*>(src);
  union { __bf16 h[4]; ushort4 s; } o;
  o.h[0] = (__bf16)f.x; o.h[1] = (__bf16)f.y; o.h[2] = (__bf16)f.z; o.h[3] = (__bf16)f.w;
  *reinterpret_cast<ushort4*>(dst) = o.s;
}

// ---------------- fused QKV projection GEMM ----------------
__global__ __launch_bounds__(256, 2) void gemm_qkv(
    const u16* __restrict__ A,
    const u16* __restrict__ W0, const u16* __restrict__ W1, const u16* __restrict__ W2,
    const float* __restrict__ b0, const float* __restrict__ b1, const float* __restrict__ b2,
    u16* __restrict__ out_q, u16* __restrict__ out_k, u16* __restrict__ out_v) {
  constexpr int K = 1024;
  __shared__ __align__(16) u16 lA[128 * 64];
  __shared__ __align__(16) u16 lB[128 * 64];
  const int w = threadIdx.x >> 6, lane = threadIdx.x & 63;
  const int blockM = blockIdx.x * 128, blockN = blockIdx.y * 128;
  const int sel = blockIdx.x >> 5;   // 0:q 1:k 2:v
  const u16*  Bt   = sel == 0 ? W0 : (sel == 1 ? W1 : W2);
  const float* bias = sel == 0 ? b0 : (sel == 1 ? b1 : b2);
  const int wm = (w >> 1) * 64, wn = (w & 1) * 64;
  f32x4 acc[4][4] = {};
  for (int kt = 0; kt < K; kt += 64) {
#pragma unroll
    for (int it = 0; it < 4; ++it) {
      int rowb = w * 32 + it * 8;
      int row  = rowb + (lane >> 3);
      int cc   = (lane & 7) * 8;
      gload16(A  + (size_t)(blockM + row) * K + kt + cc, &lA[rowb * 64]);
      gload16(Bt + (size_t)(blockN + row) * K + kt + cc, &lB[rowb * 64]);
    }
    __syncthreads();
#pragma unroll
    for (int kc = 0; kc < 2; ++kc) {
      bf16x8 af[4], bfr[4];
#pragma unroll
      for (int i = 0; i < 4; ++i)
        af[i] = *(const bf16x8*)&lA[(wm + i * 16 + (lane & 15)) * 64 + kc * 32 + (lane >> 4) * 8];
#pragma unroll
      for (int j = 0; j < 4; ++j)
        bfr[j] = *(const bf16x8*)&lB[(wn + j * 16 + (lane & 15)) * 64 + kc * 32 + (lane >> 4) * 8];
#pragma unroll
      for (int i = 0; i < 4; ++i)
#pragma unroll
        for (int j = 0; j < 4; ++j)
          acc[i][j] = __builtin_amdgcn_mfma_f32_16x16x32_bf16(af[i], bfr[j], acc[i][j], 0, 0, 0);
    }
    __syncthreads();
  }
  if (sel == 2) {
#pragma unroll
    for (int i = 0; i < 4; ++i)
#pragma unroll
      for (int j = 0; j < 4; ++j) {
        int m0 = blockM + wm + i * 16 + (lane >> 4) * 4;
        int n  = blockN + wn + j * 16 + (lane & 15);
        int ml = m0 & (MTOT - 1);
        int b = ml >> 11, s = ml & (SEQ - 1), h = n >> 6, d = n & (DK - 1);
        union { __bf16 h4[4]; ushort4 s4; } st;
#pragma unroll
        for (int r = 0; r < 4; ++r) st.h4[r] = (__bf16)(acc[i][j][r] + bias[n]);
        *(ushort4*)&out_v[(((size_t)(b * NHEADS + h)) * DK + d) * SEQ + s] = st.s4;
      }
  } else {
    u16* outqk = sel ? out_k : out_q;
#pragma unroll
    for (int i = 0; i < 4; ++i)
#pragma unroll
      for (int j = 0; j < 4; ++j)
#pragma unroll
        for (int r = 0; r < 4; ++r) {
          int m = blockM + wm + i * 16 + (lane >> 4) * 4 + r;
          int n = blockN + wn + j * 16 + (lane & 15);
          float val = acc[i][j][r] + bias[n];
          if (sel == 0) val *= QSCALE;      // fold softmax scale + log2e into q
          int ml = m & (MTOT - 1);
          int b = ml >> 11, s = ml & (SEQ - 1), h = n >> 6, d = n & (DK - 1);
          u16 bv; { union { __bf16 h2; u16 u; } cv; cv.h2 = (__bf16)val; bv = cv.u; }
          outqk[(((size_t)(b * NHEADS + h)) * SEQ + s) * DK + d] = bv;
        }
  }
}

// ---------------- output projection GEMM (64x128 tile, fp32 out) ----------------
__global__ __launch_bounds__(256, 2) void gemm_out(
    const u16* __restrict__ A, const u16* __restrict__ Bt,
    const float* __restrict__ bias, float* __restrict__ outp) {
  constexpr int K = 1024, N = 1024;
  __shared__ __align__(16) u16 lA[64 * 64];
  __shared__ __align__(16) u16 lB[128 * 64];
  const int w = threadIdx.x >> 6, lane = threadIdx.x & 63;
  const int blockM = blockIdx.x * 64, blockN = blockIdx.y * 128;
  const int wm = (w >> 1) * 32, wn = (w & 1) * 64;
  f32x4 acc[2][4] = {};
  for (int kt = 0; kt < K; kt += 64) {
#pragma unroll
    for (int it = 0; it < 2; ++it) {
      int rowb = w * 16 + it * 8;
      int row  = rowb + (lane >> 3);
      int cc   = (lane & 7) * 8;
      gload16(A + (size_t)(blockM + row) * K + kt + cc, &lA[rowb * 64]);
    }
#pragma unroll
    for (int it = 0; it < 4; ++it) {
      int rowb = w * 32 + it * 8;
      int row  = rowb + (lane >> 3);
      int cc   = (lane & 7) * 8;
      gload16(Bt + (size_t)(blockN + row) * K + kt + cc, &lB[rowb * 64]);
    }
    __syncthreads();
#pragma unroll
    for (int kc = 0; kc < 2; ++kc) {
      bf16x8 af[2], bfr[4];
#pragma unroll
      for (int i = 0; i < 2; ++i)
        af[i] = *(const bf16x8*)&lA[(wm + i * 16 + (lane & 15)) * 64 + kc * 32 + (lane >> 4) * 8];
#pragma unroll
      for (int j = 0; j < 4; ++j)
        bfr[j] = *(const bf16x8*)&lB[(wn + j * 16 + (lane & 15)) * 64 + kc * 32 + (lane >> 4) * 8];
#pragma unroll
      for (int i = 0; i < 2; ++i)
#pragma unroll
        for (int j = 0; j < 4; ++j)
          acc[i][j] = __builtin_amdgcn_mfma_f32_16x16x32_bf16(af[i], bfr[j], acc[i][j], 0, 0, 0);
    }
    __syncthreads();
  }
#pragma unroll
  for (int i = 0; i < 2; ++i)
#pragma unroll
    for (int j = 0; j < 4; ++j)
#pragma unroll
      for (int r = 0; r < 4; ++r) {
        int m = blockM + wm + i * 16 + (lane >> 4) * 4 + r;
        int n = blockN + wn + j * 16 + (lane & 15);
        outp[(size_t)m * N + n] = acc[i][j][r] + bias[n];
      }
}

// ---------------- causal flash attention ----------------
// Swapped QK^T (log2 domain, q pre-scaled), swizzled LDS, dbuf, defer-max,
// shfl_xor reductions (round-4 proven), shfl P-redistribution (round-4 proven),
// flash-decoding split (under test), XCD head clustering + LPT dispatch order.
static __device__ __forceinline__ void stage_kv(
    const u16* kp, const u16* vp, int j0,
    u16* bufK, u16* bufV, int w, int lane) {
  const int rsub = lane >> 3;                 // 0..7
  const int cl = ((lane & 7) ^ rsub) << 3;    // pre-swizzled chunk, u16 units
#pragma unroll
  for (int it = 0; it < 2; ++it) {
    const int rowb = w * 16 + it * 8;
    gload16(kp + (size_t)(j0 + rowb + rsub) * DK + cl, bufK + rowb * 64);
    gload16(vp + (size_t)(rowb + rsub) * SEQ + j0 + cl, bufV + rowb * 64);
  }
}

__global__ __launch_bounds__(256, 4) void attn_kernel(
    const u16* __restrict__ qh, const u16* __restrict__ kh,
    const u16* __restrict__ vt, u16* __restrict__ attnb,
    float* __restrict__ pO, float* __restrict__ pML) {
  __shared__ __align__(16) u16 lKV[2][2][64 * 64];   // [dbuf][K/V] = 32 KiB
  const int w = threadIdx.x >> 6, lane = threadIdx.x & 63;
  const int g = lane >> 4, q15 = lane & 15;
  // lid -> (bh, qt, half): xcd = lid&7 owns 4 heads (L2 clustering).
  // slot LPT order: 0..31 = split halves of qt 16..31, 32..47 = qt 15..0 whole.
  const int lid = blockIdx.x;                // 1536 blocks
  const int xcd = lid & 7;
  const int idx = lid >> 3;                  // 0..191
  const int p   = idx & 3;
  const int slot = idx >> 2;                 // 0..47
  const int bh = xcd * 4 + p;
  int qt, t_begin, t_end, half, split;
  if (slot < 32) {
    qt = 16 + (slot >> 1); half = slot & 1; split = 1;
    const int ntt = qt + 1, h0 = ntt >> 1;
    t_begin = half ? h0 : 0;
    t_end   = half ? ntt : h0;
  } else {
    qt = 47 - slot; half = 0; split = 0;
    t_begin = 0; t_end = qt + 1;
  }
  const int b = bh >> 4, h = bh & 15;
  const u16* qp = qh + (size_t)bh * SEQ * DK;
  const u16* kp = kh + (size_t)bh * SEQ * DK;
  const u16* vp = vt + (size_t)bh * DK * SEQ;

  const int qbase = qt * 64;
  const int qrow = qbase + w * 16 + q15;      // this lane's q-row
  bf16x8 aq[2];
  const u16* qr = qp + (size_t)qrow * DK;
#pragma unroll
  for (int kc = 0; kc < 2; ++kc)
    aq[kc] = *(const bf16x8*)(qr + kc * 32 + g * 8);

  float m_run = -1e30f, l_run = 0.f;
  f32x4 oacc[4] = {};
  stage_kv(kp, vp, t_begin * 64, lKV[t_begin & 1][0], lKV[t_begin & 1][1], w, lane);

  for (int t = t_begin; t < t_end; ++t) {
    __syncthreads();                          // tile t staged; buf cur^1 free
    const int cur = t & 1;
    if (t + 1 < t_end)
      stage_kv(kp, vp, (t + 1) * 64, lKV[cur ^ 1][0], lKV[cur ^ 1][1], w, lane);
    const u16* bK = lKV[cur][0];
    const u16* bV = lKV[cur][1];

    // S^T = K Q^T : lane holds col q = q15, rows j = nb*16 + g*4 + r (log2 domain)
    f32x4 sacc[4] = {};
    __builtin_amdgcn_s_setprio(1);
#pragma unroll
    for (int kc = 0; kc < 2; ++kc)
#pragma unroll
      for (int nb = 0; nb < 4; ++nb) {
        const int rr = nb * 16 + q15;
        const int cc = kc * 4 + g;
        bf16x8 kf = *(const bf16x8*)&bK[rr * 64 + ((cc ^ (rr & 7)) << 3)];
        sacc[nb] = __builtin_amdgcn_mfma_f32_16x16x32_bf16(kf, aq[kc], sacc[nb], 0, 0, 0);
      }
    __builtin_amdgcn_s_setprio(0);

    // per-q-row online softmax (lane-local + shfl_xor reductions, proven)
    float pvv[4][4];
    float mx = -1e30f;
    if (t == qt) {                            // diag tile: causal mask
#pragma unroll
      for (int nb = 0; nb < 4; ++nb)
#pragma unroll
        for (int r = 0; r < 4; ++r) {
          float s = sacc[nb][r];
          if (t * 64 + nb * 16 + g * 4 + r > qrow) s = -1e30f;
          pvv[nb][r] = s;
          mx = fmaxf(mx, s);
        }
    } else {
#pragma unroll
      for (int nb = 0; nb < 4; ++nb)
#pragma unroll
        for (int r = 0; r < 4; ++r) {
          float s = sacc[nb][r];
          pvv[nb][r] = s;
          mx = fmaxf(mx, s);
        }
    }
    mx = fmaxf(mx, __shfl_xor(mx, 16));
    mx = fmaxf(mx, __shfl_xor(mx, 32));
    if (__any(mx > m_run + 8.0f)) {           // defer-max
      const float mn = fmaxf(m_run, mx);
      const float alpha = __builtin_amdgcn_exp2f(m_run - mn);
      m_run = mn;
      l_run *= alpha;
#pragma unroll
      for (int nd = 0; nd < 4; ++nd)
#pragma unroll
        for (int r = 0; r < 4; ++r) oacc[nd][r] *= alpha;
    }
    float rs = 0.f;
#pragma unroll
    for (int nb = 0; nb < 4; ++nb)
#pragma unroll
      for (int r = 0; r < 4; ++r) {
        float e = __builtin_amdgcn_exp2f(pvv[nb][r] - m_run);
        pvv[nb][r] = e;
        rs += e;
      }
    rs += __shfl_xor(rs, 16);
    rs += __shfl_xor(rs, 32);
    l_run += rs;

    // pack P pairs (v_cvt_pk_bf16_f32)
    uint32_t pk[4][2];
#pragma unroll
    for (int nb = 0; nb < 4; ++nb) {
      union { __bf16 h2[2]; uint32_t u; } t0, t1;
      t0.h2[0] = (__bf16)pvv[nb][0]; t0.h2[1] = (__bf16)pvv[nb][1];
      t1.h2[0] = (__bf16)pvv[nb][2]; t1.h2[1] = (__bf16)pvv[nb][3];
      pk[nb][0] = t0.u; pk[nb][1] = t1.u;
    }

    // O^T += V^T P^T : B-frag word W from lane ((g&1)*2+(W>>1))*16+q15 (proven shfl path)
#pragma unroll
    for (int jc = 0; jc < 2; ++jc) {
      union { u32x4 u; bf16x8 bvec; } pf;
      const int sgbase = (g & 1) * 2;
#pragma unroll
      for (int W = 0; W < 4; ++W) {
        const int src = (sgbase + (W >> 1)) * 16 + q15;
        const uint32_t lo = (uint32_t)__shfl((int)pk[2 * jc][W & 1], src, 64);
        const uint32_t hi = (uint32_t)__shfl((int)pk[2 * jc + 1][W & 1], src, 64);
        pf.u[W] = (lane >= 32) ? hi : lo;
      }
      __builtin_amdgcn_s_setprio(1);
#pragma unroll
      for (int nd = 0; nd < 4; ++nd) {
        const int rr = nd * 16 + q15;
        const int cc = jc * 4 + g;
        bf16x8 vf = *(const bf16x8*)&bV[rr * 64 + ((cc ^ (rr & 7)) << 3)];
        oacc[nd] = __builtin_amdgcn_mfma_f32_16x16x32_bf16(vf, pf.bvec, oacc[nd], 0, 0, 0);
      }
      __builtin_amdgcn_s_setprio(0);
    }
  }

  if (!split) {
    // epilogue: lane owns q-row qrow; oacc[nd][r] = O[qrow][nd*16 + g*4 + r]
    const float rl = 1.0f / l_run;
#pragma unroll
    for (int nd = 0; nd < 4; ++nd) {
      union { __bf16 h4[4]; ushort4 s4; } st;
      st.h4[0] = (__bf16)(oacc[nd][0] * rl);
      st.h4[1] = (__bf16)(oacc[nd][1] * rl);
      st.h4[2] = (__bf16)(oacc[nd][2] * rl);
      st.h4[3] = (__bf16)(oacc[nd][3] * rl);
      *(ushort4*)&attnb[((size_t)(b * SEQ + qrow)) * D_MODEL + h * 64 + nd * 16 + g * 4] = st.s4;
    }
  } else {
    // write unnormalized partial O + (m,l) for the combine kernel
    const int pid = ((bh << 4) + (qt - 16)) * 2 + half;
    float* po = pO + (size_t)pid * 4096 + (w * 16 + q15) * 64;
#pragma unroll
    for (int nd = 0; nd < 4; ++nd)
      *(f32x4*)(po + nd * 16 + g * 4) = oacc[nd];
    if (g == 0) {
      float2 ml; ml.x = m_run; ml.y = l_run;
      ((float2*)pML)[pid * 64 + w * 16 + q15] = ml;
    }
  }
}

// ---------------- combine partials for split qt ----------------
__global__ __launch_bounds__(256) void attn_combine(
    const float* __restrict__ pO, const float* __restrict__ pML,
    u16* __restrict__ attnb) {
  const int blk = blockIdx.x;          // 512 = 32 bh x 16 qti
  const int bh = blk >> 4, qti = blk & 15;
  const int qt = 16 + qti;
  const int b = bh >> 4, h = bh & 15;
  const int pid0 = ((bh << 4) + qti) * 2;
  const int t = threadIdx.x;
  const int row = t >> 2, c0 = (t & 3) * 16;
  const float2 ml0 = ((const float2*)pML)[pid0 * 64 + row];
  const float2 ml1 = ((const float2*)pML)[(pid0 + 1) * 64 + row];
  const float M = fmaxf(ml0.x, ml1.x);
  const float w0 = __builtin_amdgcn_exp2f(ml0.x - M);
  const float w1 = __builtin_amdgcn_exp2f(ml1.x - M);
  const float inv = 1.0f / (ml0.y * w0 + ml1.y * w1);
  const float s0 = w0 * inv, s1 = w1 * inv;
  const float* O0 = pO + (size_t)pid0 * 4096 + row * 64 + c0;
  const float* O1 = O0 + 4096;
  u16* dst = attnb + ((size_t)(b * SEQ + qt * 64 + row)) * D_MODEL + h * 64 + c0;
#pragma unroll
  for (int c = 0; c < 4; ++c) {
    float4 a  = *(const float4*)(O0 + c * 4);
    float4 d2 = *(const float4*)(O1 + c * 4);
    union { __bf16 h4[4]; ushort4 s4; } st;
    st.h4[0] = (__bf16)(a.x * s0 + d2.x * s1);
    st.h4[1] = (__bf16)(a.y * s0 + d2.y * s1);
    st.h4[2] = (__bf16)(a.z * s0 + d2.z * s1);
    st.h4[3] = (__bf16)(a.w * s0 + d2.w * s1);
    *(ushort4*)(dst + c * 4) = st.s4;
  }
}

// ---------------- launcher ----------------
extern "C" void kernel_launch(void* const* d_in, const int* in_sizes, int n_in,
                              void* d_out, int out_size, void* d_ws, size_t ws_size,
                              hipStream_t stream) {
  (void)in_sizes; (void)n_in; (void)out_size; (void)ws_size;
  const float* Q  = (const float*)d_in[0];
  const float* K  = (const float*)d_in[1];
  const float* V  = (const float*)d_in[2];
  // d_in[3] = mask — causal, implemented analytically
  const float* Wq = (const float*)d_in[4];
  const float* bq = (const float*)d_in[5];
  const float* Wk = (const float*)d_in[6];
  const float* bk = (const float*)d_in[7];
  const float* Wv = (const float*)d_in[8];
  const float* bv = (const float*)d_in[9];
  const float* Wo = (const float*)d_in[10];
  const float* bo = (const float*)d_in[11];

  char* ws = (char*)d_ws;
  size_t off = 0;
  auto carve = [&](size_t bytes) { char* p = ws + off; off += bytes; return p; };
  const size_t szX = (size_t)MTOT * D_MODEL * 2;       // 8 MB
  const size_t szW = (size_t)D_MODEL * D_MODEL * 2;    // 2 MB
  u16* Qb  = (u16*)carve(szX);   // [Qb|Kb|Vb] contiguous
  u16* Kb  = (u16*)carve(szX);
  u16* Vb  = (u16*)carve(szX);
  u16* Wqb = (u16*)carve(szW);   // [Wqb|Wkb|Wvb|Wob] contiguous
  u16* Wkb = (u16*)carve(szW);
  u16* Wvb = (u16*)carve(szW);
  u16* Wob = (u16*)carve(szW);
  u16* qhB = (u16*)carve(szX);
  u16* khB = (u16*)carve(szX);
  u16* vtB = (u16*)carve(szX);
  u16* attnb = Qb;               // Qb dead after gemm_qkv
  float* pO  = (float*)Kb;       // Kb+Vb = 16 MB, dead after gemm_qkv (1024 x 16KB partial O)
  float* pML = (float*)Wqb;      // 512 KB, Wqb dead after gemm_qkv
  (void)Wkb; (void)Wvb;

  const int nTot = 3 * MTOT * D_MODEL + 4 * D_MODEL * D_MODEL;  // 16M elems
  cast_all_kernel<<<nTot / 1024, 256, 0, stream>>>(Q, K, V, Wq, Wk, Wv, Wo, Qb, Wqb);

  gemm_qkv<<<dim3(3 * MTOT / 128, D_MODEL / 128), 256, 0, stream>>>(
      Qb, Wqb, Wkb, Wvb, bq, bk, bv, qhB, khB, vtB);

  attn_kernel<<<1536, 256, 0, stream>>>(qhB, khB, vtB, attnb, pO, pML);

  attn_combine<<<512, 256, 0, stream>>>(pO, pML, attnb);

  gemm_out<<<dim3(MTOT / 64, D_MODEL / 128), 256, 0, stream>>>(attnb, Wob, bo, (float*)d_out);
}